// Round 5
// baseline (1629.486 us; speedup 1.0000x reference)
//
#include <hip/hip_runtime.h>
#include <hip/hip_bf16.h>
#include <cstddef>
#include <cstdint>

#define NAU 50000
#define NPA 100000
#define KH 8
#define DH 32
#define KD 256
#define DIN 128
#define SLOPE 0.2f

typedef __attribute__((ext_vector_type(8))) short short8;
typedef __attribute__((ext_vector_type(4))) float f32x4;

__device__ __forceinline__ float leakyf(float x) { return x >= 0.f ? x : SLOPE * x; }

__device__ __forceinline__ ushort f2b(float f) {
  __hip_bfloat16 h = __float2bfloat16(f);
  return *reinterpret_cast<ushort*>(&h);
}
__device__ __forceinline__ float b2f(ushort u) {
  __hip_bfloat16 h;
  *reinterpret_cast<ushort*>(&h) = u;
  return __bfloat162float(h);
}

// ---------------- MFMA split-bf16 GEMM ----------------
// C[M,256] = sum_p A_p[M,Kp] @ B_p[Kp,256]  (hi/lo bf16 split per product)
// 256 thr = 4 waves; tile 64x64; wave 32x32 = 2x2 frags 16x16x32.
// LDS: [64 rows][64 ushorts] = hi k0..31 | lo k0..31, 128B rows,
// XOR-swizzled 16B slots (slot ^= row&7) -> ds_read_b128 frags.

__device__ __forceinline__ short8 ldfrag8(const ushort (*P)[64], int row, int slot) {
  return *reinterpret_cast<const short8*>(&P[row][((slot ^ (row & 7)) << 3)]);
}

template<int NP, int EPI>
__global__ __launch_bounds__(256) void k_mfma(
    const float* __restrict__ A0, int K0, const ushort* __restrict__ B0h, const ushort* __restrict__ B0l,
    const float* __restrict__ A1, int K1, const ushort* __restrict__ B1h, const ushort* __restrict__ B1l,
    const float* __restrict__ A2, int K2, const ushort* __restrict__ B2h, const ushort* __restrict__ B2l,
    int M,
    const float* __restrict__ bres, const float* __restrict__ resw,
    const float* __restrict__ wwp, const float* __restrict__ wcp,
    float* __restrict__ outp)
{
  __shared__ ushort As[64][64];
  __shared__ ushort Bs[64][64];
  const int tid = threadIdx.x;

  // bijective XCD swizzle: the 4 col-blocks of a row-tile run consecutively
  // on the same XCD -> A re-reads hit that XCD's L2.
  const int nwg = gridDim.x;
  int orig = blockIdx.x;
  int q = nwg >> 3, r8 = nwg & 7, xc = orig & 7, jj = orig >> 3;
  int wg = (xc < r8 ? xc * (q + 1) : r8 * (q + 1) + (xc - r8) * q) + jj;
  const int row0 = (wg >> 2) * 64, col0 = (wg & 3) * 64;

  const int wid = tid >> 6, lane = tid & 63;
  const int wr = wid >> 1, wc = wid & 1;
  const int kq = lane >> 4, rr = lane & 15;
  const int sr = tid >> 2;           // staging row 0..63
  const int sq = tid & 3;            // 16B quarter (k-window sq*8..sq*8+7)
  const int swz = sr & 7;

  f32x4 acc[NP][2][2] = {};

  const float*  Aps[3] = {A0, A1, A2};
  const ushort* Bhs[3] = {B0h, B1h, B2h};
  const ushort* Bls[3] = {B0l, B1l, B2l};
  const int     Kds[3] = {K0, K1, K2};

#pragma unroll
  for (int p = 0; p < NP; ++p) {
    const float*  A  = Aps[p];
    const ushort* Bh = Bhs[p];
    const ushort* Bl = Bls[p];
    const int     Kd = Kds[p];
    for (int k0 = 0; k0 < Kd; k0 += 32) {
      __syncthreads();
      // stage A: f32 -> hi/lo split (mask-truncate hi, exact residual lo)
      {
        int gr = row0 + sr;
        float4 v0 = make_float4(0.f, 0.f, 0.f, 0.f), v1 = v0;
        if (gr < M) {
          const float* ap = A + (size_t)gr * Kd + k0 + sq * 8;
          v0 = *reinterpret_cast<const float4*>(ap);
          v1 = *reinterpret_cast<const float4*>(ap + 4);
        }
        float f[8] = {v0.x, v0.y, v0.z, v0.w, v1.x, v1.y, v1.z, v1.w};
        uint hv[4], lv[4];
#pragma unroll
        for (int i = 0; i < 4; ++i) {
          uint ua = __float_as_uint(f[2 * i]);
          uint ub = __float_as_uint(f[2 * i + 1]);
          uint ma = ua & 0xffff0000u;
          uint mb = ub & 0xffff0000u;
          hv[i] = (ua >> 16) | mb;
          float la = f[2 * i] - __uint_as_float(ma);
          float lb = f[2 * i + 1] - __uint_as_float(mb);
          lv[i] = (__float_as_uint(la) >> 16) | (__float_as_uint(lb) & 0xffff0000u);
        }
        *reinterpret_cast<int4*>(&As[sr][((sq ^ swz) << 3)]) =
            make_int4((int)hv[0], (int)hv[1], (int)hv[2], (int)hv[3]);
        *reinterpret_cast<int4*>(&As[sr][(((sq + 4) ^ swz) << 3)]) =
            make_int4((int)lv[0], (int)lv[1], (int)lv[2], (int)lv[3]);
      }
      // stage B^T planes [256][Kd]
      {
        const size_t bo = (size_t)(col0 + sr) * Kd + k0 + sq * 8;
        *reinterpret_cast<int4*>(&Bs[sr][((sq ^ swz) << 3)]) =
            *reinterpret_cast<const int4*>(Bh + bo);
        *reinterpret_cast<int4*>(&Bs[sr][(((sq + 4) ^ swz) << 3)]) =
            *reinterpret_cast<const int4*>(Bl + bo);
      }
      __syncthreads();

      short8 ah[2], al[2], bh[2], bl[2];
#pragma unroll
      for (int fm = 0; fm < 2; ++fm) {
        int row = wr * 32 + fm * 16 + rr;
        ah[fm] = ldfrag8(As, row, kq);
        al[fm] = ldfrag8(As, row, kq + 4);
      }
#pragma unroll
      for (int fn = 0; fn < 2; ++fn) {
        int nrow = wc * 32 + fn * 16 + rr;
        bh[fn] = ldfrag8(Bs, nrow, kq);
        bl[fn] = ldfrag8(Bs, nrow, kq + 4);
      }
#pragma unroll
      for (int fm = 0; fm < 2; ++fm)
#pragma unroll
        for (int fn = 0; fn < 2; ++fn) {
          f32x4 c = acc[p][fm][fn];
          c = __builtin_amdgcn_mfma_f32_16x16x32_bf16(ah[fm], bh[fn], c, 0, 0, 0);
          c = __builtin_amdgcn_mfma_f32_16x16x32_bf16(ah[fm], bl[fn], c, 0, 0, 0);
          c = __builtin_amdgcn_mfma_f32_16x16x32_bf16(al[fm], bh[fn], c, 0, 0, 0);
          acc[p][fm][fn] = c;
        }
    }
  }

  // epilogue: C/D layout col=lane&15, row=(lane>>4)*4+reg
  float g = 0.f;
  if constexpr (EPI >= 1) g = 1.f / (1.f + __expf(-resw[0]));
#pragma unroll
  for (int fm = 0; fm < 2; ++fm)
#pragma unroll
    for (int fn = 0; fn < 2; ++fn) {
      int cc = col0 + wc * 32 + fn * 16 + rr;
#pragma unroll
      for (int i = 0; i < 4; ++i) {
        int r = row0 + wr * 32 + fm * 16 + kq * 4 + i;
        if (r < M) {
          if constexpr (EPI == 0) {
            outp[(size_t)r * KD + cc] = acc[0][fm][fn][i];
          } else if constexpr (EPI == 1) {
            float o = g * acc[0][fm][fn][i] + (1.f - g) * (acc[1][fm][fn][i] + bres[cc]);
            outp[(size_t)r * KD + cc] = o;
          } else {
            int head = cc >> 5;
            float wwv = wwp[(size_t)r * KH + head];
            float wcv = wcp[(size_t)r * KH + head];
            float o = g * (wwv * acc[0][fm][fn][i] + wcv * acc[1][fm][fn][i])
                    + (1.f - g) * (acc[2][fm][fn][i] + bres[cc]);
            outp[(size_t)r * KD + cc] = o;
          }
        }
      }
    }
}

// weights W[K][256] f32 -> transposed hi/lo bf16 planes [256][K]
__global__ void k_prepB(const float* __restrict__ W, int Kd,
                        ushort* __restrict__ Bh, ushort* __restrict__ Bl) {
  int idx = blockIdx.x * 256 + threadIdx.x;
  if (idx >= Kd * 256) return;
  int n = idx / Kd, k = idx - n * Kd;
  float v = W[(size_t)k * 256 + n];
  ushort h = f2b(v);
  Bh[idx] = h;
  Bl[idx] = f2b(v - b2f(h));
}

// per-node attention dots
__global__ void k_node_dots(
    const float* __restrict__ f, int N,
    const float* __restrict__ a0, float* __restrict__ o0,
    const float* __restrict__ a1, float* __restrict__ o1,
    const float* __restrict__ a2, float* __restrict__ o2)
{
  int idx = blockIdx.x * blockDim.x + threadIdx.x;
  if (idx >= N * KH) return;
  int n = idx >> 3, k = idx & 7;
  const float* fr = f + (size_t)n * KD + k * DH;
  float d0 = 0.f, d1 = 0.f, d2 = 0.f;
#pragma unroll
  for (int i = 0; i < DH; i += 4) {
    float4 fv = *reinterpret_cast<const float4*>(fr + i);
    if (a0) {
      float4 v = *reinterpret_cast<const float4*>(a0 + k * 64 + i);
      d0 += fv.x * v.x + fv.y * v.y + fv.z * v.z + fv.w * v.w;
    }
    if (a1) {
      float4 v = *reinterpret_cast<const float4*>(a1 + k * 64 + i);
      d1 += fv.x * v.x + fv.y * v.y + fv.z * v.z + fv.w * v.w;
    }
    if (a2) {
      float4 v = *reinterpret_cast<const float4*>(a2 + k * 64 + i);
      d2 += fv.x * v.x + fv.y * v.y + fv.z * v.z + fv.w * v.w;
    }
  }
  if (o0) o0[idx] = d0;
  if (o1) o1[idx] = d1;
  if (o2) o2[idx] = d2;
}

// ---------------- CSR build ----------------
__global__ void k_hist(const int* __restrict__ dst, int E, int* __restrict__ cnt) {
  int e = blockIdx.x * 256 + threadIdx.x;
  if (e < E) atomicAdd(&cnt[dst[e]], 1);
}

__global__ void k_scan1(const int* __restrict__ cnt, int n,
                        int* __restrict__ off, int* __restrict__ bsum) {
  __shared__ int sm[256];
  int t = threadIdx.x;
  int i = blockIdx.x * 256 + t;
  int v = (i < n) ? cnt[i] : 0;
  sm[t] = v; __syncthreads();
  for (int o = 1; o < 256; o <<= 1) {
    int x = (t >= o) ? sm[t - o] : 0;
    __syncthreads();
    sm[t] += x;
    __syncthreads();
  }
  if (i < n) off[i] = sm[t] - v;
  if (t == 255) bsum[blockIdx.x] = sm[255];
}

__global__ void k_scan2(int* __restrict__ bsum, int nb) {
  __shared__ int sm[512];
  int t = threadIdx.x;
  int v = (t < nb) ? bsum[t] : 0;
  sm[t] = v; __syncthreads();
  for (int o = 1; o < 512; o <<= 1) {
    int x = (t >= o) ? sm[t - o] : 0;
    __syncthreads();
    sm[t] += x;
    __syncthreads();
  }
  if (t < nb) bsum[t] = sm[t] - v;
}

__global__ void k_scan3(int* __restrict__ off, int n, const int* __restrict__ bsum) {
  int i = blockIdx.x * 256 + threadIdx.x;
  if (i < n) off[i] += bsum[blockIdx.x];
}

__global__ void k_scatter(const int* __restrict__ dst, int E,
                          const int* __restrict__ off, int* __restrict__ cur,
                          int* __restrict__ eidx) {
  int e = blockIdx.x * 256 + threadIdx.x;
  if (e >= E) return;
  int d = dst[e];
  int p = atomicAdd(&cur[d], 1);
  eidx[off[d] + p] = e;
}

// ---------------- dst-centric fused attention + aggregation ----------------
// 4-deep prefetch; optional fused macro score with FULL 256-column reduction:
//   sc[d,k] = sum_{t=0..255} relu_out[t] * effv[t*8+k]   (all 8 k per thread)
__global__ __launch_bounds__(256) void k_agg_dst(
    const int* __restrict__ eidx, const int* __restrict__ off_,
    const int* __restrict__ cnt_, const int* __restrict__ src,
    const float* __restrict__ el, const float* __restrict__ er,
    const float* __restrict__ fs,
    const float* __restrict__ effv, float* __restrict__ scout,
    float* __restrict__ outp)
{
  __shared__ int ssi[256];
  __shared__ float red[4][8];
  int d = blockIdx.x;
  int t = threadIdx.x;
  int k = t >> 5;
  int c = cnt_[d];
  float acc = 0.f, s = 0.f;
  if (c > 0) {
    int base = off_[d];
    float erk = er[(size_t)d * KH + k];
    for (int j0 = 0; j0 < c; j0 += 256) {
      int m = min(256, c - j0);
      __syncthreads();
      if (t < m) ssi[t] = src[eidx[base + j0 + t]];
      __syncthreads();
      for (int j = 0; j < m; j += 4) {
        int i1 = min(j + 1, m - 1), i2 = min(j + 2, m - 1), i3 = min(j + 3, m - 1);
        int s0 = ssi[j], s1 = ssi[i1], s2 = ssi[i2], s3 = ssi[i3];
        float v0 = fs[(size_t)s0 * KD + t];
        float v1 = fs[(size_t)s1 * KD + t];
        float v2 = fs[(size_t)s2 * KD + t];
        float v3 = fs[(size_t)s3 * KD + t];
        float e0 = el[(size_t)s0 * KH + k];
        float e1 = el[(size_t)s1 * KH + k];
        float e2 = el[(size_t)s2 * KH + k];
        float e3 = el[(size_t)s3 * KH + k];
        float a0 = __expf(leakyf(e0 + erk));
        float a1 = (j + 1 < m) ? __expf(leakyf(e1 + erk)) : 0.f;
        float a2 = (j + 2 < m) ? __expf(leakyf(e2 + erk)) : 0.f;
        float a3 = (j + 3 < m) ? __expf(leakyf(e3 + erk)) : 0.f;
        s += (a0 + a1) + (a2 + a3);
        acc = fmaf(v0, a0, acc);
        acc = fmaf(v1, a1, acc);
        acc = fmaf(v2, a2, acc);
        acc = fmaf(v3, a3, acc);
      }
    }
    acc = fmaxf(acc / s, 0.f);
  }
  outp[(size_t)d * KD + t] = acc;
  if (effv) {
    // per-thread contribution to ALL 8 heads, then block-wide reduce
    float4 e0 = *reinterpret_cast<const float4*>(effv + t * KH);
    float4 e1 = *reinterpret_cast<const float4*>(effv + t * KH + 4);
    float pk[8] = {acc * e0.x, acc * e0.y, acc * e0.z, acc * e0.w,
                   acc * e1.x, acc * e1.y, acc * e1.z, acc * e1.w};
#pragma unroll
    for (int o = 1; o < 64; o <<= 1) {
#pragma unroll
      for (int kk = 0; kk < 8; ++kk) pk[kk] += __shfl_xor(pk[kk], o);
    }
    int wv = t >> 6, ln = t & 63;
    if (ln == 0) {
#pragma unroll
      for (int kk = 0; kk < 8; ++kk) red[wv][kk] = pk[kk];
    }
    __syncthreads();
    if (t < KH)
      scout[(size_t)d * KH + t] = (red[0][t] + red[1][t]) + (red[2][t] + red[3][t]);
  }
}

// tiny pre-contractions
__global__ void k_weff(
    const float* __restrict__ Wmnp, const float* __restrict__ Wrw,
    const float* __restrict__ Wrc, const float* __restrict__ attn,
    float* __restrict__ enp, float* __restrict__ ew, float* __restrict__ ec)
{
  int idx = blockIdx.x * blockDim.x + threadIdx.x;
  if (idx < DIN * KH) {
    int c = idx >> 3, k = idx & 7;
    float sum = 0.f;
    for (int d = 0; d < DH; ++d) sum += Wmnp[(size_t)c * KD + k * DH + d] * attn[k * 64 + d];
    enp[idx] = sum;
  } else if (idx < DIN * KH + KD * KH) {
    int j = idx - DIN * KH;
    int c = j >> 3, k = j & 7;
    float sum = 0.f;
    for (int d = 0; d < DH; ++d) sum += Wrw[(size_t)c * KD + k * DH + d] * attn[k * 64 + 32 + d];
    ew[j] = sum;
  } else if (idx < DIN * KH + 2 * KD * KH) {
    int j = idx - DIN * KH - KD * KH;
    int c = j >> 3, k = j & 7;
    float sum = 0.f;
    for (int d = 0; d < DH; ++d) sum += Wrc[(size_t)c * KD + k * DH + d] * attn[k * 64 + 32 + d];
    ec[j] = sum;
  }
}

// skinny GEMM: out[M,8] = A[M,Kdim] @ W[Kdim,8]
template<bool RELU>
__global__ __launch_bounds__(256) void k_skinny(
    const float* __restrict__ A, int M, int Kdim,
    const float* __restrict__ W, float* __restrict__ outp)
{
  __shared__ float Ws[KD * KH];
  int tid = threadIdx.x;
  for (int i = tid; i < Kdim * KH; i += 256) Ws[i] = W[i];
  __syncthreads();
  int r = blockIdx.x * 32 + (tid >> 3);
  int k = tid & 7;
  if (r >= M) return;
  const float* Ar = A + (size_t)r * Kdim;
  float acc = 0.f;
  for (int c = 0; c < Kdim; c += 4) {
    float4 av = *reinterpret_cast<const float4*>(Ar + c);
    if (RELU) {
      av.x = fmaxf(av.x, 0.f); av.y = fmaxf(av.y, 0.f);
      av.z = fmaxf(av.z, 0.f); av.w = fmaxf(av.w, 0.f);
    }
    acc += av.x * Ws[(c + 0) * KH + k] + av.y * Ws[(c + 1) * KH + k]
         + av.z * Ws[(c + 2) * KH + k] + av.w * Ws[(c + 3) * KH + k];
  }
  outp[(size_t)r * KH + k] = acc;
}

// macro softmax weights over 2 relations
__global__ void k_weights(
    const float* __restrict__ npdot, const float* __restrict__ scw,
    const float* __restrict__ scc, float* __restrict__ ww,
    float* __restrict__ wc, int N8)
{
  int idx = blockIdx.x * blockDim.x + threadIdx.x;
  if (idx >= N8) return;
  float nd = npdot[idx];
  float lw = leakyf(nd + scw[idx]);
  float lc = leakyf(nd + scc[idx]);
  float m = fmaxf(lw, lc);
  float e1 = __expf(lw - m), e2 = __expf(lc - m);
  float inv = 1.f / (e1 + e2);
  ww[idx] = e1 * inv;
  wc[idx] = e2 * inv;
}

static inline void run_relation(hipStream_t stream,
                                const int* src, const int* dst, int E, int n_dst,
                                int* cnt, int* cur, int* off, int* bsum, int* eidx,
                                const float* el, const float* er,
                                const float* fs, const float* effv, float* scout,
                                float* outp) {
  hipMemsetAsync(cnt, 0, (size_t)n_dst * sizeof(int), stream);
  hipMemsetAsync(cur, 0, (size_t)n_dst * sizeof(int), stream);
  int nb = (n_dst + 255) / 256;
  k_hist<<<(E + 255) / 256, 256, 0, stream>>>(dst, E, cnt);
  k_scan1<<<nb, 256, 0, stream>>>(cnt, n_dst, off, bsum);
  k_scan2<<<1, 512, 0, stream>>>(bsum, nb);
  k_scan3<<<nb, 256, 0, stream>>>(off, n_dst, bsum);
  k_scatter<<<(E + 255) / 256, 256, 0, stream>>>(dst, E, off, cur, eidx);
  k_agg_dst<<<n_dst, 256, 0, stream>>>(eidx, off, cnt, src, el, er, fs, effv, scout, outp);
}

extern "C" void kernel_launch(void* const* d_in, const int* in_sizes, int n_in,
                              void* d_out, int out_size, void* d_ws, size_t ws_size,
                              hipStream_t stream)
{
  const float* feat_a  = (const float*)d_in[0];
  const float* feat_p  = (const float*)d_in[1];
  const float* W_mic_a = (const float*)d_in[2];
  const float* W_mic_p = (const float*)d_in[3];
  const float* attn_a  = (const float*)d_in[4];
  const float* attn_p  = (const float*)d_in[5];
  const float* W_mnp   = (const float*)d_in[7];
  const float* W_rw    = (const float*)d_in[8];
  const float* W_rwb   = (const float*)d_in[9];
  const float* W_rc    = (const float*)d_in[10];
  const float* attn_m  = (const float*)d_in[11];
  const float* W_res_a = (const float*)d_in[12];
  const float* b_res_a = (const float*)d_in[13];
  const float* W_res_p = (const float*)d_in[14];
  const float* b_res_p = (const float*)d_in[15];
  const float* rw_a    = (const float*)d_in[16];
  const float* rw_p    = (const float*)d_in[17];
  const int* w_src  = (const int*)d_in[18];
  const int* w_dst  = (const int*)d_in[19];
  const int* wbsrc  = (const int*)d_in[20];
  const int* wbdst  = (const int*)d_in[21];
  const int* c_src  = (const int*)d_in[22];
  const int* c_dst  = (const int*)d_in[23];
  const int Ew = in_sizes[18], Ewb = in_sizes[20], Ec = in_sizes[22];

  float* ws = (float*)d_ws;
  const size_t SA = (size_t)NAU * KD;      // 12.8M
  const size_t SP = (size_t)NPA * KD;      // 25.6M
  float* fa    = ws;                       // SA
  float* fp    = fa + SA;                  // SP
  float* r_w   = fp + SP;                  // SP
  float* r_wb  = r_w + SP;                 // SA
  float* r_c   = r_wb + SA;                // SP
  float* elA   = r_c + SP;
  float* erA   = elA + (size_t)NAU * KH;
  float* elP   = erA + (size_t)NAU * KH;
  float* erPa  = elP + (size_t)NPA * KH;
  float* erPp  = erPa + (size_t)NPA * KH;
  float* npdot = erPp + (size_t)NPA * KH;
  float* scw   = npdot + (size_t)NPA * KH;
  float* scc   = scw + (size_t)NPA * KH;
  float* wwb   = scc + (size_t)NPA * KH;
  float* wcb   = wwb + (size_t)NPA * KH;
  float* effnp = wcb + (size_t)NPA * KH;   // 128*8
  float* effw  = effnp + DIN * KH;         // 256*8
  float* effc  = effw + KD * KH;           // 256*8
  // bf16 transposed weight planes (ushort), 16B-aligned region
  ushort* bt = (ushort*)(effc + KD * KH);
  ushort* BTmicA_h = bt;                  bt += 256 * DIN;
  ushort* BTmicA_l = bt;                  bt += 256 * DIN;
  ushort* BTmicP_h = bt;                  bt += 256 * DIN;
  ushort* BTmicP_l = bt;                  bt += 256 * DIN;
  ushort* BTrwb_h  = bt;                  bt += 256 * KD;
  ushort* BTrwb_l  = bt;                  bt += 256 * KD;
  ushort* BTrw_h   = bt;                  bt += 256 * KD;
  ushort* BTrw_l   = bt;                  bt += 256 * KD;
  ushort* BTrc_h   = bt;                  bt += 256 * KD;
  ushort* BTrc_l   = bt;                  bt += 256 * KD;
  ushort* BTresA_h = bt;                  bt += 256 * DIN;
  ushort* BTresA_l = bt;                  bt += 256 * DIN;
  ushort* BTresP_h = bt;                  bt += 256 * DIN;
  ushort* BTresP_l = bt;                  bt += 256 * DIN;
  int*   cnt   = (int*)bt;
  int*   cur   = cnt + NPA;
  int*   off   = cur + NPA;
  int*   bsum  = off + NPA;                // 512
  int*   eidx  = bsum + 512;               // up to 1M

  float* out_a = (float*)d_out;
  float* out_p = (float*)d_out + SA;

  // weight prep (transpose + hi/lo split) + macro pre-contractions
  k_prepB<<<DIN, 256, 0, stream>>>(W_mic_a, DIN, BTmicA_h, BTmicA_l);
  k_prepB<<<DIN, 256, 0, stream>>>(W_mic_p, DIN, BTmicP_h, BTmicP_l);
  k_prepB<<<KD,  256, 0, stream>>>(W_rwb,  KD,  BTrwb_h,  BTrwb_l);
  k_prepB<<<KD,  256, 0, stream>>>(W_rw,   KD,  BTrw_h,   BTrw_l);
  k_prepB<<<KD,  256, 0, stream>>>(W_rc,   KD,  BTrc_h,   BTrc_l);
  k_prepB<<<DIN, 256, 0, stream>>>(W_res_a, DIN, BTresA_h, BTresA_l);
  k_prepB<<<DIN, 256, 0, stream>>>(W_res_p, DIN, BTresP_h, BTresP_l);
  k_weff<<<20, 256, 0, stream>>>(W_mnp, W_rw, W_rc, attn_m, effnp, effw, effc);

  // micro projections (MFMA)
  {
    int nwg = ((NAU + 63) / 64) * 4;
    k_mfma<1, 0><<<nwg, 256, 0, stream>>>(
        feat_a, DIN, BTmicA_h, BTmicA_l,
        nullptr, 0, nullptr, nullptr, nullptr, 0, nullptr, nullptr,
        NAU, nullptr, nullptr, nullptr, nullptr, fa);
  }
  {
    int nwg = ((NPA + 63) / 64) * 4;
    k_mfma<1, 0><<<nwg, 256, 0, stream>>>(
        feat_p, DIN, BTmicP_h, BTmicP_l,
        nullptr, 0, nullptr, nullptr, nullptr, 0, nullptr, nullptr,
        NPA, nullptr, nullptr, nullptr, nullptr, fp);
  }

  // node attention dots
  k_node_dots<<<(NAU * KH + 255) / 256, 256, 0, stream>>>(
      fa, NAU, attn_a, elA, attn_p + 32, erA, nullptr, nullptr);
  k_node_dots<<<(NPA * KH + 255) / 256, 256, 0, stream>>>(
      fp, NPA, attn_p, elP, attn_a + 32, erPa, attn_p + 32, erPp);

  // relations: CSR build + dst-centric fused aggregation (+ fused macro scores)
  run_relation(stream, w_src, w_dst, Ew, NPA, cnt, cur, off, bsum, eidx,
               elA, erPa, fa, effw, scw, r_w);
  run_relation(stream, wbsrc, wbdst, Ewb, NAU, cnt, cur, off, bsum, eidx,
               elP, erA, fp, nullptr, nullptr, r_wb);
  run_relation(stream, c_src, c_dst, Ec, NPA, cnt, cur, off, bsum, eidx,
               elP, erPp, fp, effc, scc, r_c);

  // out_a: fused rel+residual (MFMA)
  {
    int nwg = ((NAU + 63) / 64) * 4;
    k_mfma<2, 1><<<nwg, 256, 0, stream>>>(
        r_wb, KD, BTrwb_h, BTrwb_l,
        feat_a, DIN, BTresA_h, BTresA_l,
        nullptr, 0, nullptr, nullptr,
        NAU, b_res_a, rw_a, nullptr, nullptr, out_a);
  }

  // macro attention weights
  k_skinny<false><<<(NPA + 31) / 32, 256, 0, stream>>>(feat_p, NPA, DIN, effnp, npdot);
  k_weights<<<(NPA * KH + 255) / 256, 256, 0, stream>>>(npdot, scw, scc, wwb, wcb, NPA * KH);

  // out_p: fused triple GEMM with macro weights + residual (MFMA)
  {
    int nwg = ((NPA + 63) / 64) * 4;
    k_mfma<3, 2><<<nwg, 256, 0, stream>>>(
        r_w, KD, BTrw_h, BTrw_l,
        r_c, KD, BTrc_h, BTrc_l,
        feat_p, DIN, BTresP_h, BTresP_l,
        NPA, b_res_p, rw_p, wwb, wcb, out_p);
  }
}